// Round 3
// baseline (2579.840 us; speedup 1.0000x reference)
//
#include <hip/hip_runtime.h>
#include <math.h>

#define B   64
#define T   512
#define I0  256
#define H   512
#define M   (B*T)

#define NGR 4            // batch groups (16 rows each -> MFMA M=16)
#define BGR 16
#define RSLOTS 8         // ring depth (power of 2)
#define SLOT_US (B*H)    // 32768 us per slot (all groups)
#define GRP_US  (BGR*H)  // 8192 us per group region within a slot
#define RING_US ((size_t)RSLOTS*SLOT_US)   // 512KB per ring
#define RESET_D 4        // reset slot r+4 (data of step r-4; safe, skew<=1)
#define POLL_BUDGET 1000000L

typedef __attribute__((ext_vector_type(8))) short short8;
typedef __attribute__((ext_vector_type(4))) float floatx4;
typedef unsigned long long u64;

static __device__ __forceinline__ unsigned short f2bf(float f) {
  unsigned u = __float_as_uint(f);
  u += 0x7fff + ((u >> 16) & 1);          // RNE
  return (unsigned short)(u >> 16);
}

// fast tanh: 1 - 2/(e^{2x}+1). |err| ~1e-6, saturates correctly at +/-1.
static __device__ __forceinline__ float ftanh(float x) {
  float e = __expf(2.0f * x);
  return 1.0f - 2.0f * __builtin_amdgcn_rcpf(e + 1.0f);
}

// nonzero iff any halfword of v == 0xFFFF (the bf16 sentinel)
static __device__ __forceinline__ u64 sentmask(u64 v) {
  u64 w = ~v;
  return (w - 0x0001000100010001ULL) & ~w & 0x8000800080008000ULL;
}

// ---------------------------------------------------------------------------
// fp32 GEMM for layer-1 input projection: xw[M,H] = x[M,I0] * Wih0[H,I0]^T
// ---------------------------------------------------------------------------
template<int K>
__global__ __launch_bounds__(256)
void gemm_awt(const float* __restrict__ A, const float* __restrict__ W,
              float* __restrict__ C) {
  __shared__ float As[16][68];
  __shared__ float Bs[16][68];
  const int tid = threadIdx.x;
  const int tx = tid & 15, ty = tid >> 4;
  const int m0 = blockIdx.x * 64, n0 = blockIdx.y * 64;
  float acc[4][4] = {};
  for (int k0 = 0; k0 < K; k0 += 16) {
    {
      int e = tid * 4;
      int m = e >> 4, k = e & 15;
      float4 v = *(const float4*)&A[(m0 + m) * K + k0 + k];
      As[k][m] = v.x; As[k+1][m] = v.y; As[k+2][m] = v.z; As[k+3][m] = v.w;
      float4 w = *(const float4*)&W[(n0 + m) * K + k0 + k];
      Bs[k][m] = w.x; Bs[k+1][m] = w.y; Bs[k+2][m] = w.z; Bs[k+3][m] = w.w;
    }
    __syncthreads();
    #pragma unroll
    for (int k = 0; k < 16; ++k) {
      float a[4], w[4];
      *(float4*)a = *(const float4*)&As[k][ty*4];
      *(float4*)w = *(const float4*)&Bs[k][tx*4];
      #pragma unroll
      for (int i = 0; i < 4; ++i)
        #pragma unroll
        for (int j = 0; j < 4; ++j)
          acc[i][j] += a[i] * w[j];
    }
    __syncthreads();
  }
  #pragma unroll
  for (int i = 0; i < 4; ++i) {
    float4 r;
    r.x = acc[i][0]; r.y = acc[i][1]; r.z = acc[i][2]; r.w = acc[i][3];
    *(float4*)&C[(m0 + ty*4 + i) * H + n0 + tx*4] = r;
  }
}

// ---------------------------------------------------------------------------
// Pack [H,H] fp32 weight into bf16 B-fragment lane order:
// dst layout [tile=32][kt=16][lane=64][8 us]
// ---------------------------------------------------------------------------
__global__ __launch_bounds__(256)
void pack_w(const float* __restrict__ W, unsigned short* __restrict__ dst) {
  int idx = blockIdx.x * 256 + threadIdx.x;   // over 16*2*16*64 = 32768
  int l = idx & 63, i = (idx >> 6) & 15, tau = (idx >> 10) & 1, c = idx >> 11;
  int col = c * 32 + tau * 16 + (l & 15);
  int k0  = i * 32 + (l >> 4) * 8;
  const float* src = &W[col * H + k0];
  unsigned v[4];
  #pragma unroll
  for (int j = 0; j < 4; ++j) {
    unsigned lo = f2bf(src[2*j]);
    unsigned hi = f2bf(src[2*j + 1]);
    v[j] = lo | (hi << 16);
  }
  *(uint4*)&dst[(size_t)idx * 8] = make_uint4(v[0], v[1], v[2], v[3]);
}

// ---------------------------------------------------------------------------
// Merged-layer wave-autonomous recurrence. 64 blocks x 1 wave:
// block (g, wp) owns batch rows [g*16,g*16+16) and cols [wp*32, wp*32+32)
// of BOTH layers. Per step r: one sentinel-poll of ring0[r-1] + ring1[r-2]
// (fragment-layout, fully coalesced 16B/lane loads -> the winning loads ARE
// the MFMA A-operands), then L1 MFMA->store (critical broadcast first),
// then L2 MFMA->store+dout. The same hv fragments feed L1's Whh0 term AND
// L2's Wih1 term (L2 lags L1 by exactly 1 step, by construction -> no
// back-pressure, no progress array, no h1 cross-poll).
// Ring layout [slot][g][kt=16][lane=64][8 us]: producer (g,wp) scatters its
// 16x32 tile into region kt=wp; consumer lane l reads contiguous 16B at
// (kt*64+l)*16B. Sentinel 0xFFFF (-NaN bf16, tanh never produces it);
// each thread resets its OWN addresses RESET_D slots ahead.
// ---------------------------------------------------------------------------
__global__ __launch_bounds__(64)
void rnn_fused(const float* __restrict__ xw,
               const unsigned short* __restrict__ wp0,  // Whh0 packed
               const unsigned short* __restrict__ wp1,  // Wih1 packed
               const unsigned short* __restrict__ wp2,  // Whh1 packed
               unsigned short* __restrict__ ring0,      // [RSLOTS][B][H] bf16
               unsigned short* __restrict__ ring1,
               float* __restrict__ dout)                // [B][T][H]
{
  __shared__ unsigned short wi_lds[16384];   // Wih1 tile-pair (32KB)
  const int lane = threadIdx.x;
  const int mrow = lane & 15, quad = lane >> 4;
  const int g  = blockIdx.x & 3;
  const int wp = blockIdx.x >> 2;            // 0..15 col chunk
  const int b0 = g * BGR;
  const int c0 = wp * 32;

  // recurrence-critical weights -> registers (2 tiles each)
  short8 wa0[16], wa1[16], wb0[16], wb1[16];
  #pragma unroll
  for (int kt = 0; kt < 16; ++kt) {
    wa0[kt] = *(const short8*)(wp0 + (size_t)(((2*wp    )*16 + kt)*64 + lane)*8);
    wa1[kt] = *(const short8*)(wp0 + (size_t)(((2*wp + 1)*16 + kt)*64 + lane)*8);
    wb0[kt] = *(const short8*)(wp2 + (size_t)(((2*wp    )*16 + kt)*64 + lane)*8);
    wb1[kt] = *(const short8*)(wp2 + (size_t)(((2*wp + 1)*16 + kt)*64 + lane)*8);
  }
  {   // Wih1 tile-pair -> LDS (off the ring-critical chains)
    const uint4* s = (const uint4*)(wp1 + (size_t)(2*wp) * 8192);
    uint4* d = (uint4*)wi_lds;
    for (int i = lane; i < 2048; i += 64) d[i] = s[i];
  }
  __syncthreads();

  // per-thread fragment-layout store offsets (halfwords within group region)
  int soff0, soff1;
  {
    int ca = mrow;        soff0 = wp*512 + (ca>>3)*128 + (ca&7);
    int cb = 16 + mrow;   soff1 = wp*512 + (cb>>3)*128 + (cb&7);
  }

  u64 hv[32], gv[32];
  long cnt = 0;

  for (int r = 0; r <= T; ++r) {
    // ---- xw prefetch (latency hides under the poll)
    float xv0[4], xv1[4];
    if (r < T) {
      #pragma unroll
      for (int i = 0; i < 4; ++i) {
        size_t base = ((size_t)(b0 + quad*4 + i) * T + r) * H;
        xv0[i] = xw[base + c0 + mrow];
        xv1[i] = xw[base + c0 + 16 + mrow];
      }
    }

    const bool needg = (r >= 2);
    if (r >= 1) {
      // ---- single coalesced sentinel-poll for both rings
      const u64* rb0 = (const u64*)(ring0
          + (size_t)((r-1) & (RSLOTS-1)) * SLOT_US + g * GRP_US);
      const u64* rb1 = (const u64*)(ring1
          + (size_t)((r-2) & (RSLOTS-1)) * SLOT_US + g * GRP_US);
      for (;;) {
        #pragma unroll
        for (int kt = 0; kt < 16; ++kt) {
          hv[2*kt]   = __hip_atomic_load(rb0 + kt*128 + lane*2,
                                         __ATOMIC_RELAXED, __HIP_MEMORY_SCOPE_AGENT);
          hv[2*kt+1] = __hip_atomic_load(rb0 + kt*128 + lane*2 + 1,
                                         __ATOMIC_RELAXED, __HIP_MEMORY_SCOPE_AGENT);
        }
        if (needg) {
          #pragma unroll
          for (int kt = 0; kt < 16; ++kt) {
            gv[2*kt]   = __hip_atomic_load(rb1 + kt*128 + lane*2,
                                           __ATOMIC_RELAXED, __HIP_MEMORY_SCOPE_AGENT);
            gv[2*kt+1] = __hip_atomic_load(rb1 + kt*128 + lane*2 + 1,
                                           __ATOMIC_RELAXED, __HIP_MEMORY_SCOPE_AGENT);
          }
        }
        u64 bad = 0;
        #pragma unroll
        for (int j = 0; j < 32; ++j) bad |= sentmask(hv[j]);
        if (needg) {
          #pragma unroll
          for (int j = 0; j < 32; ++j) bad |= sentmask(gv[j]);
        }
        if (__all(bad == 0) || ++cnt > POLL_BUDGET) break;
      }
    }

    // ---- layer 1: h1[r] (critical broadcast — do FIRST, store immediately)
    if (r < T) {
      floatx4 a0 = {0.f,0.f,0.f,0.f}, a1 = {0.f,0.f,0.f,0.f};
      if (r >= 1) {
        #pragma unroll
        for (int kt = 0; kt < 16; ++kt) {
          union { u64 u[2]; short8 s; } a;
          a.u[0] = hv[2*kt]; a.u[1] = hv[2*kt+1];
          a0 = __builtin_amdgcn_mfma_f32_16x16x32_bf16(a.s, wa0[kt], a0, 0, 0, 0);
          a1 = __builtin_amdgcn_mfma_f32_16x16x32_bf16(a.s, wa1[kt], a1, 0, 0, 0);
        }
      }
      unsigned short* wdst = ring0 + (size_t)(r & (RSLOTS-1)) * SLOT_US + g*GRP_US;
      unsigned short* wrst = ring0 + (size_t)((r+RESET_D) & (RSLOTS-1)) * SLOT_US + g*GRP_US;
      #pragma unroll
      for (int i = 0; i < 4; ++i) {
        int ro = (quad*4 + i) * 8;
        __hip_atomic_store(wdst + soff0 + ro, f2bf(ftanh(a0[i] + xv0[i])),
                           __ATOMIC_RELAXED, __HIP_MEMORY_SCOPE_AGENT);
        __hip_atomic_store(wdst + soff1 + ro, f2bf(ftanh(a1[i] + xv1[i])),
                           __ATOMIC_RELAXED, __HIP_MEMORY_SCOPE_AGENT);
      }
      #pragma unroll
      for (int i = 0; i < 4; ++i) {    // own-address sentinel resets
        int ro = (quad*4 + i) * 8;
        __hip_atomic_store(wrst + soff0 + ro, (unsigned short)0xFFFFu,
                           __ATOMIC_RELAXED, __HIP_MEMORY_SCOPE_AGENT);
        __hip_atomic_store(wrst + soff1 + ro, (unsigned short)0xFFFFu,
                           __ATOMIC_RELAXED, __HIP_MEMORY_SCOPE_AGENT);
      }
    }
    __builtin_amdgcn_sched_barrier(0);   // keep L2 work after the L1 store

    // ---- layer 2: h2[r-1] (Wih1 term reuses hv; Whh1 term uses gv)
    if (r >= 1) {
      floatx4 p0 = {0.f,0.f,0.f,0.f}, p1 = {0.f,0.f,0.f,0.f};
      #pragma unroll
      for (int kt = 0; kt < 16; ++kt) {
        union { u64 u[2]; short8 s; } a;
        a.u[0] = hv[2*kt]; a.u[1] = hv[2*kt+1];
        short8 bi0 = *(const short8*)(wi_lds + ((size_t)(kt     )*64 + lane)*8);
        short8 bi1 = *(const short8*)(wi_lds + ((size_t)(16 + kt)*64 + lane)*8);
        p0 = __builtin_amdgcn_mfma_f32_16x16x32_bf16(a.s, bi0, p0, 0, 0, 0);
        p1 = __builtin_amdgcn_mfma_f32_16x16x32_bf16(a.s, bi1, p1, 0, 0, 0);
      }
      if (needg) {
        #pragma unroll
        for (int kt = 0; kt < 16; ++kt) {
          union { u64 u[2]; short8 s; } a;
          a.u[0] = gv[2*kt]; a.u[1] = gv[2*kt+1];
          p0 = __builtin_amdgcn_mfma_f32_16x16x32_bf16(a.s, wb0[kt], p0, 0, 0, 0);
          p1 = __builtin_amdgcn_mfma_f32_16x16x32_bf16(a.s, wb1[kt], p1, 0, 0, 0);
        }
      }
      const int t2 = r - 1;
      unsigned short* wdst = ring1 + (size_t)(t2 & (RSLOTS-1)) * SLOT_US + g*GRP_US;
      unsigned short* wrst = ring1 + (size_t)((t2+RESET_D) & (RSLOTS-1)) * SLOT_US + g*GRP_US;
      #pragma unroll
      for (int i = 0; i < 4; ++i) {
        int ro = (quad*4 + i) * 8;
        float v0 = ftanh(p0[i]);
        float v1 = ftanh(p1[i]);
        __hip_atomic_store(wdst + soff0 + ro, f2bf(v0),
                           __ATOMIC_RELAXED, __HIP_MEMORY_SCOPE_AGENT);
        __hip_atomic_store(wdst + soff1 + ro, f2bf(v1),
                           __ATOMIC_RELAXED, __HIP_MEMORY_SCOPE_AGENT);
        int b = b0 + quad*4 + i;
        dout[((size_t)b * T + t2) * H + c0 + mrow]      = v0;
        dout[((size_t)b * T + t2) * H + c0 + 16 + mrow] = v1;
      }
      #pragma unroll
      for (int i = 0; i < 4; ++i) {
        int ro = (quad*4 + i) * 8;
        __hip_atomic_store(wrst + soff0 + ro, (unsigned short)0xFFFFu,
                           __ATOMIC_RELAXED, __HIP_MEMORY_SCOPE_AGENT);
        __hip_atomic_store(wrst + soff1 + ro, (unsigned short)0xFFFFu,
                           __ATOMIC_RELAXED, __HIP_MEMORY_SCOPE_AGENT);
      }
    }
  }
}

extern "C" void kernel_launch(void* const* d_in, const int* in_sizes, int n_in,
                              void* d_out, int out_size, void* d_ws, size_t ws_size,
                              hipStream_t stream) {
  const float* x    = (const float*)d_in[0];
  const float* Wih0 = (const float*)d_in[1];
  const float* Whh0 = (const float*)d_in[2];
  const float* Wih1 = (const float*)d_in[3];
  const float* Whh1 = (const float*)d_in[4];
  float* out = (float*)d_out;

  char* ws = (char*)d_ws;
  float* xw = (float*)ws;
  unsigned short* wp0 = (unsigned short*)(ws + (size_t)64*1024*1024);
  unsigned short* wp1 = (unsigned short*)(ws + (size_t)64*1024*1024 + 512*1024);
  unsigned short* wp2 = (unsigned short*)(ws + (size_t)64*1024*1024 + 1024*1024);
  unsigned short* ring0 = (unsigned short*)(ws + (size_t)64*1024*1024 + 1536*1024);
  unsigned short* ring1 = ring0 + RING_US;

  // sentinel-fill both rings (0xFFFF bf16 = -NaN; tanh never produces it)
  hipMemsetAsync(ring0, 0xFF, 2 * RING_US * sizeof(unsigned short), stream);

  pack_w<<<128, 256, 0, stream>>>(Whh0, wp0);
  pack_w<<<128, 256, 0, stream>>>(Wih1, wp1);
  pack_w<<<128, 256, 0, stream>>>(Whh1, wp2);

  dim3 gg(M/64, H/64);
  gemm_awt<I0><<<gg, 256, 0, stream>>>(x, Wih0, xw);

  rnn_fused<<<NGR * 16, 64, 0, stream>>>(
      xw, wp0, wp1, wp2, ring0, ring1, out);
}